// Round 7
// baseline (537.098 us; speedup 1.0000x reference)
//
#include <hip/hip_runtime.h>
#include <hip/hip_fp16.h>

// GCN 3-layer, fp16 intermediates, f32 accum, MFMA GEMMs, atomic-lean CSR build.
// per layer: h = (x*ns) @ W ; agg = scatter_sum_dst(h[src]) ; out = agg*nd + b ; relu(0,1)
// norm_src folded into agg epilogue of previous layer (relu(x)*s == relu(x*s), s>0).

typedef _Float16 h8 __attribute__((ext_vector_type(8)));
typedef float f32x4 __attribute__((ext_vector_type(4)));

// ---------------- utility ----------------
__global__ void k_zero_i32(int* __restrict__ p, int n) {
    int i = blockIdx.x * blockDim.x + threadIdx.x;
    int stride = gridDim.x * blockDim.x;
    for (; i < n; i += stride) p[i] = 0;
}

// ---------------- count degrees + capture per-edge position (4-way ILP) ----------------
__global__ void k_count(const int* __restrict__ src, const int* __restrict__ dst, int E,
                        int* __restrict__ deg_o, int* __restrict__ deg_i,
                        int* __restrict__ pos) {
    const int stride = gridDim.x * blockDim.x;
    int i = blockIdx.x * blockDim.x + threadIdx.x;
    for (; i + 3 * stride < E; i += 4 * stride) {
        const int i1 = i + stride, i2 = i + 2 * stride, i3 = i + 3 * stride;
        int s0 = src[i], s1 = src[i1], s2 = src[i2], s3 = src[i3];
        int d0 = dst[i], d1 = dst[i1], d2 = dst[i2], d3 = dst[i3];
        atomicAdd(&deg_o[s0], 1);   // fire-and-forget
        atomicAdd(&deg_o[s1], 1);
        atomicAdd(&deg_o[s2], 1);
        atomicAdd(&deg_o[s3], 1);
        int p0 = atomicAdd(&deg_i[d0], 1);  // 4 outstanding returning atomics
        int p1 = atomicAdd(&deg_i[d1], 1);
        int p2 = atomicAdd(&deg_i[d2], 1);
        int p3 = atomicAdd(&deg_i[d3], 1);
        __builtin_nontemporal_store(p0, &pos[i]);
        __builtin_nontemporal_store(p1, &pos[i1]);
        __builtin_nontemporal_store(p2, &pos[i2]);
        __builtin_nontemporal_store(p3, &pos[i3]);
    }
    for (; i < E; i += stride) {
        atomicAdd(&deg_o[src[i]], 1);
        pos[i] = atomicAdd(&deg_i[dst[i]], 1);
    }
}

// ---------------- scan1 + norms fused ----------------
__global__ __launch_bounds__(256) void k_scan1(const int* __restrict__ deg_i,
                                               const int* __restrict__ deg_o,
                                               int* __restrict__ rp,
                                               int* __restrict__ bsum,
                                               float* __restrict__ ns,
                                               float* __restrict__ nd, int n) {
    const int tid = threadIdx.x, lane = tid & 63, wid = tid >> 6;
    int i = blockIdx.x * 256 + tid;
    int v = (i < n) ? deg_i[i] : 0;
    if (i < n) {
        nd[i] = rsqrtf((float)max(v, 1));
        ns[i] = rsqrtf((float)max(deg_o[i], 1));
    }
    int x = v;
#pragma unroll
    for (int off = 1; off < 64; off <<= 1) {
        int t = __shfl_up(x, off, 64);
        if (lane >= off) x += t;
    }
    __shared__ int ws[4];
    if (lane == 63) ws[wid] = x;
    __syncthreads();
    int wo = 0;
    for (int k = 0; k < wid; ++k) wo += ws[k];
    int incl = wo + x;
    if (i < n) rp[i] = incl - v;  // block-local exclusive
    if (tid == 255) bsum[blockIdx.x] = incl;  // block total
}

__global__ __launch_bounds__(512) void k_scan2(int* __restrict__ bsum, int nb,
                                               int* __restrict__ rpN) {
    __shared__ int s[512];
    const int tid = threadIdx.x;
    int v = (tid < nb) ? bsum[tid] : 0;
    s[tid] = v;
    __syncthreads();
    for (int off = 1; off < 512; off <<= 1) {
        int t = (tid >= off) ? s[tid - off] : 0;
        __syncthreads();
        s[tid] += t;
        __syncthreads();
    }
    if (tid < nb) bsum[tid] = s[tid] - v;  // exclusive
    if (tid == nb - 1) *rpN = s[tid];      // grand total -> rp[N]
}

__global__ void k_scan3(int* __restrict__ rp, const int* __restrict__ bsum, int n) {
    int i = blockIdx.x * blockDim.x + threadIdx.x;
    if (i < n) rp[i] += bsum[i >> 8];
}

// ---------------- mega: CSR scatter | prepX0 | prepW (block-range partitioned) ----------------
__global__ __launch_bounds__(256) void k_mega(
        const int* __restrict__ src, const int* __restrict__ dst, int E,
        const int* __restrict__ rp, const int* __restrict__ pos, int* __restrict__ csr,
        const float* __restrict__ feat, const float* __restrict__ ns,
        __half* __restrict__ X, int n,
        const float* __restrict__ W0, const float* __restrict__ W1,
        const float* __restrict__ W2,
        __half* __restrict__ Wt0, __half* __restrict__ Wt1, __half* __restrict__ Wt2) {
    const int b = blockIdx.x;
    if (b < 1024) {
        // CSR scatter (no atomics)
        int i = b * 256 + threadIdx.x;
        const int stride = 1024 * 256;
        for (; i < E; i += stride) {
            int p = __builtin_nontemporal_load(&pos[i]);
            csr[rp[dst[i]] + p] = src[i];
        }
    } else if (b < 2048) {
        // X0 = (half)(feat * ns[row]) as float4 chunks
        int i = (b - 1024) * 256 + threadIdx.x;
        const int total = n * 32;  // N*128/4
        const int stride = 1024 * 256;
        for (; i < total; i += stride) {
            int row = i >> 5;
            float s = ns[row];
            float4 v = ((const float4*)feat)[i];
            __half2 h0 = __floats2half2_rn(v.x * s, v.y * s);
            __half2 h1 = __floats2half2_rn(v.z * s, v.w * s);
            uint2 packed = make_uint2(*(unsigned*)&h0, *(unsigned*)&h1);
            *(uint2*)(X + (size_t)i * 4) = packed;
        }
    } else {
        // weight transpose+cast: Wt[n][k] = (half)W[k][n]
        int idx = (b - 2048) * 256 + threadIdx.x;  // 0..40959
        if (idx < 16384) {
            int nn = idx >> 7, k = idx & 127;
            Wt0[idx] = __float2half(W0[k * 128 + nn]);
        } else if (idx < 32768) {
            int j = idx - 16384;
            int nn = j >> 7, k = j & 127;
            Wt1[j] = __float2half(W1[k * 128 + nn]);
        } else if (idx < 40960) {
            int j = idx - 32768;
            int nn = j >> 7, k = j & 127;
            Wt2[j] = __float2half(W2[k * 64 + nn]);
        }
    }
}

// ---------------- MFMA GEMM: C[n,BN] = X[n,128] @ Wt[BN,128]^T, fp16 in/out ----------------
// v_mfma_f32_16x16x32_f16: A/B frag = 8 contiguous-K halves/lane at k=8*(lane>>4),
// row/col = lane&15. C/D: col=lane&15, row=(lane>>4)*4+reg (guide m89-verified).
template <int BN>
__global__ __launch_bounds__(256) void k_gemm_mfma(const __half* __restrict__ X,
                                                   const __half* __restrict__ Wt,
                                                   __half* __restrict__ C, int n) {
    constexpr int K = 128, BM = 128, PAD = 8, LDR = K + PAD;  // halves
    __shared__ __half Al[BM * LDR];
    __shared__ __half Bl[BN * LDR];
    const int tid = threadIdx.x;
    const int row0 = blockIdx.x * BM;
    // stage A tile (BM x 128 halves), fully coalesced 16B chunks
    {
        const float4 z = make_float4(0.f, 0.f, 0.f, 0.f);
#pragma unroll
        for (int q = 0; q < 8; ++q) {
            int fi = q * 256 + tid;            // float4 index within tile
            int r = fi >> 4, c = (fi & 15) * 8;
            int gr = row0 + r;
            float4 v = (gr < n) ? *(const float4*)(X + (size_t)gr * K + c) : z;
            *(float4*)&Al[r * LDR + c] = v;
        }
    }
    // stage Wt tile (BN x 128 halves)
    {
#pragma unroll
        for (int q = 0; q < BN / 16; ++q) {
            int fi = q * 256 + tid;
            int r = fi >> 4, c = (fi & 15) * 8;
            *(float4*)&Bl[r * LDR + c] = *(const float4*)(Wt + (size_t)r * K + c);
        }
    }
    __syncthreads();
    const int wid = tid >> 6, lane = tid & 63;
    const int lo = lane & 15, hi = lane >> 4;
    constexpr int NC = BN / 16;
    f32x4 acc[2][NC];
#pragma unroll
    for (int t = 0; t < 2; ++t)
#pragma unroll
        for (int c = 0; c < NC; ++c) acc[t][c] = (f32x4){0.f, 0.f, 0.f, 0.f};
#pragma unroll
    for (int kc = 0; kc < 4; ++kc) {
        h8 aF[2];
#pragma unroll
        for (int t = 0; t < 2; ++t)
            aF[t] = *(const h8*)&Al[(32 * wid + 16 * t + lo) * LDR + 32 * kc + 8 * hi];
#pragma unroll
        for (int c = 0; c < NC; ++c) {
            h8 bF = *(const h8*)&Bl[(16 * c + lo) * LDR + 32 * kc + 8 * hi];
#pragma unroll
            for (int t = 0; t < 2; ++t)
                acc[t][c] = __builtin_amdgcn_mfma_f32_16x16x32_f16(aF[t], bF, acc[t][c], 0, 0, 0);
        }
    }
    // store: row = row0 + 32*wid + 16*t + 4*hi + j, col = 16*c + lo
#pragma unroll
    for (int t = 0; t < 2; ++t) {
#pragma unroll
        for (int j = 0; j < 4; ++j) {
            int gr = row0 + 32 * wid + 16 * t + 4 * hi + j;
            if (gr < n) {
#pragma unroll
                for (int c = 0; c < NC; ++c)
                    C[(size_t)gr * BN + 16 * c + lo] = __float2half(acc[t][c][j]);
            }
        }
    }
}

// ---------------- aggregation D=128 fp16 in, fp16 out (pre-scaled by ns) ----------------
template <bool RELU>
__global__ __launch_bounds__(256) void k_agg128h(const __half2* __restrict__ H,  // [N][64] half2
                                                 const int* __restrict__ rp,
                                                 const int* __restrict__ cs,
                                                 const float* __restrict__ nd,
                                                 const float* __restrict__ ns,
                                                 const float* __restrict__ b,
                                                 __half2* __restrict__ out, int n) {
    const int wid = threadIdx.x >> 6, lane = threadIdx.x & 63;
    const int node = blockIdx.x * 4 + wid;
    if (node >= n) return;
    const int beg = rp[node], end = rp[node + 1];
    float2 a0 = make_float2(0.f, 0.f), a1 = a0, a2 = a0, a3 = a0;
    int e = beg;
    for (; e + 3 < end; e += 4) {
        int s0 = __builtin_nontemporal_load(&cs[e]);
        int s1 = __builtin_nontemporal_load(&cs[e + 1]);
        int s2 = __builtin_nontemporal_load(&cs[e + 2]);
        int s3 = __builtin_nontemporal_load(&cs[e + 3]);
        float2 v0 = __half22float2(H[(size_t)s0 * 64 + lane]);
        float2 v1 = __half22float2(H[(size_t)s1 * 64 + lane]);
        float2 v2 = __half22float2(H[(size_t)s2 * 64 + lane]);
        float2 v3 = __half22float2(H[(size_t)s3 * 64 + lane]);
        a0.x += v0.x; a0.y += v0.y;
        a1.x += v1.x; a1.y += v1.y;
        a2.x += v2.x; a2.y += v2.y;
        a3.x += v3.x; a3.y += v3.y;
    }
    for (; e < end; ++e) {
        int s0 = __builtin_nontemporal_load(&cs[e]);
        float2 v0 = __half22float2(H[(size_t)s0 * 64 + lane]);
        a0.x += v0.x; a0.y += v0.y;
    }
    const float sc = nd[node];
    const float sn = ns[node];
    float2 bb = ((const float2*)b)[lane];
    float ox = (a0.x + a1.x + a2.x + a3.x) * sc + bb.x;
    float oy = (a0.y + a1.y + a2.y + a3.y) * sc + bb.y;
    if (RELU) { ox = fmaxf(ox, 0.f); oy = fmaxf(oy, 0.f); }
    ox *= sn; oy *= sn;
    __half2 hv = __floats2half2_rn(ox, oy);
    __builtin_nontemporal_store(*(unsigned*)&hv, (unsigned*)&out[(size_t)node * 64 + lane]);
}

// ---------------- aggregation D=64 fp16 in, f32 out, no relu, no ns fold ----------------
__global__ __launch_bounds__(256) void k_agg64h(const __half* __restrict__ H,  // [N][64]
                                                const int* __restrict__ rp,
                                                const int* __restrict__ cs,
                                                const float* __restrict__ nd,
                                                const float* __restrict__ b,
                                                float* __restrict__ out, int n) {
    const int wid = threadIdx.x >> 6, lane = threadIdx.x & 63;
    const int node = blockIdx.x * 4 + wid;
    if (node >= n) return;
    const int beg = rp[node], end = rp[node + 1];
    float a0 = 0.f, a1 = 0.f, a2 = 0.f, a3 = 0.f;
    int e = beg;
    for (; e + 3 < end; e += 4) {
        int s0 = __builtin_nontemporal_load(&cs[e]);
        int s1 = __builtin_nontemporal_load(&cs[e + 1]);
        int s2 = __builtin_nontemporal_load(&cs[e + 2]);
        int s3 = __builtin_nontemporal_load(&cs[e + 3]);
        a0 += __half2float(H[(size_t)s0 * 64 + lane]);
        a1 += __half2float(H[(size_t)s1 * 64 + lane]);
        a2 += __half2float(H[(size_t)s2 * 64 + lane]);
        a3 += __half2float(H[(size_t)s3 * 64 + lane]);
    }
    for (; e < end; ++e) {
        int s0 = __builtin_nontemporal_load(&cs[e]);
        a0 += __half2float(H[(size_t)s0 * 64 + lane]);
    }
    float o = (a0 + a1 + a2 + a3) * nd[node] + b[lane];
    __builtin_nontemporal_store(o, &out[(size_t)node * 64 + lane]);
}

extern "C" void kernel_launch(void* const* d_in, const int* in_sizes, int n_in,
                              void* d_out, int out_size, void* d_ws, size_t ws_size,
                              hipStream_t stream) {
    const float* feat = (const float*)d_in[0];
    const int* ei = (const int*)d_in[1];
    const float* W0 = (const float*)d_in[2];
    const float* b0 = (const float*)d_in[3];
    const float* W1 = (const float*)d_in[4];
    const float* b1 = (const float*)d_in[5];
    const float* W2 = (const float*)d_in[6];
    const float* b2 = (const float*)d_in[7];
    float* out = (float*)d_out;

    const int N = in_sizes[0] / 128;  // 100000
    const int E = in_sizes[1] / 2;    // 1600000
    const int* src = ei;
    const int* dst = ei + E;
    const int NB = (N + 255) / 256;   // scan blocks (391 <= 512)

    // workspace layout (16B-aligned chunks)
    char* w = (char*)d_ws;
    float* norm_src = (float*)w; w += (size_t)N * 4;
    float* norm_dst = (float*)w; w += (size_t)N * 4;
    int* deg_o = (int*)w;        w += (size_t)N * 4;   // deg_o,deg_i contiguous (zero 2N)
    int* deg_i = (int*)w;        w += (size_t)N * 4;
    int* rp    = (int*)w;        w += ((size_t)(N + 1) * 4 + 15) / 16 * 16;
    int* bsum  = (int*)w;        w += 512 * 4;
    int* pos   = (int*)w;        w += (size_t)E * 4;
    int* csr   = (int*)w;        w += (size_t)E * 4;
    __half* Wt0 = (__half*)w;    w += 128 * 128 * 2;
    __half* Wt1 = (__half*)w;    w += 128 * 128 * 2;
    __half* Wt2 = (__half*)w;    w += 128 * 64 * 2;
    __half* Xb = (__half*)w;     w += (size_t)N * 128 * 2;  // GEMM input
    __half* Hb = (__half*)w;     w += (size_t)N * 128 * 2;  // GEMM output (gather src)

    // ---- CSR build (one atomic pass) ----
    k_zero_i32<<<512, 256, 0, stream>>>(deg_o, 2 * N);
    k_count<<<1024, 256, 0, stream>>>(src, dst, E, deg_o, deg_i, pos);
    k_scan1<<<NB, 256, 0, stream>>>(deg_i, deg_o, rp, bsum, norm_src, norm_dst, N);
    k_scan2<<<1, 512, 0, stream>>>(bsum, NB, rp + N);
    k_scan3<<<NB, 256, 0, stream>>>(rp, bsum, N);
    // ---- scatter + prepX0 + prepW fused ----
    k_mega<<<2048 + 160, 256, 0, stream>>>(src, dst, E, rp, pos, csr,
                                           feat, norm_src, Xb, N,
                                           W0, W1, W2, Wt0, Wt1, Wt2);

    const int gemm_grid = (N + 127) / 128;
    const int agg_grid = (N + 3) / 4;

    // layer 0
    k_gemm_mfma<128><<<gemm_grid, 256, 0, stream>>>(Xb, Wt0, Hb, N);
    k_agg128h<true><<<agg_grid, 256, 0, stream>>>((const __half2*)Hb, rp, csr, norm_dst,
                                                  norm_src, b0, (__half2*)Xb, N);
    // layer 1
    k_gemm_mfma<128><<<gemm_grid, 256, 0, stream>>>(Xb, Wt1, Hb, N);
    k_agg128h<true><<<agg_grid, 256, 0, stream>>>((const __half2*)Hb, rp, csr, norm_dst,
                                                  norm_src, b1, (__half2*)Xb, N);
    // layer 2 (BN=64, no relu, f32 out)
    k_gemm_mfma<64><<<gemm_grid, 256, 0, stream>>>(Xb, Wt2, Hb, N);
    k_agg64h<<<agg_grid, 256, 0, stream>>>(Hb, rp, csr, norm_dst, b2, out, N);
}

// Round 8
// 465.791 us; speedup vs baseline: 1.1531x; 1.1531x over previous
//
#include <hip/hip_runtime.h>
#include <hip/hip_fp16.h>

// GCN 3-layer: fp16 intermediates, f32 accum, MFMA GEMMs (in-kernel W transpose),
// CSR build overlapped with layer-0 GEMM (block-partitioned fused kernel).
// Math: (x*ns)@W == (x@W)*ns_row; layer-0 folds ns[src] into the gather (fma),
// later layers pre-scale the agg output by ns (relu(x)*s == relu(x*s), s>0).

typedef _Float16 h8 __attribute__((ext_vector_type(8)));
typedef float f32x4 __attribute__((ext_vector_type(4)));

// ---------------- utility ----------------
__global__ void k_zero_i32(int* __restrict__ p, int n) {
    int i = blockIdx.x * blockDim.x + threadIdx.x;
    int stride = gridDim.x * blockDim.x;
    for (; i < n; i += stride) p[i] = 0;
}

// ---------------- shared GEMM body: C[n,BN](fp16) = A[n,128] @ W[128,BN] ----------------
// W is f32 row-major [K][BN]; transposed+cast to LDS in-kernel.
// v_mfma_f32_16x16x32_f16; A/B frag = 8 halves at k=8*(lane>>4), row/col=lane&15;
// C/D: col=lane&15, row=(lane>>4)*4+reg (guide m89-verified; round-6 validated).
template <int BN, bool F32A>
__device__ __forceinline__ void gemm_body(const void* __restrict__ Ap,
                                          const float* __restrict__ W,
                                          __half* __restrict__ C, int n, int gb) {
    constexpr int K = 128, BM = 128, LDR = K + 8;  // halves; 272B rows (16B aligned)
    __shared__ __half Al[BM * LDR];
    __shared__ __half Bl[BN * LDR];
    const int tid = threadIdx.x;
    const int row0 = gb * BM;
    if (F32A) {
        const float* A = (const float*)Ap;
#pragma unroll
        for (int q = 0; q < 16; ++q) {
            int fi = q * 256 + tid;
            int r = fi >> 5, c = (fi & 31) * 4;
            int gr = row0 + r;
            float4 v = make_float4(0.f, 0.f, 0.f, 0.f);
            if (gr < n) v = *(const float4*)(A + (size_t)gr * K + c);
            __half2 h0 = __floats2half2_rn(v.x, v.y);
            __half2 h1 = __floats2half2_rn(v.z, v.w);
            uint2 pk = make_uint2(*(unsigned*)&h0, *(unsigned*)&h1);
            *(uint2*)&Al[r * LDR + c] = pk;
        }
    } else {
        const __half* A = (const __half*)Ap;
#pragma unroll
        for (int q = 0; q < 8; ++q) {
            int fi = q * 256 + tid;
            int r = fi >> 4, c = (fi & 15) * 8;
            int gr = row0 + r;
            float4 v = make_float4(0.f, 0.f, 0.f, 0.f);
            if (gr < n) v = *(const float4*)(A + (size_t)gr * K + c);
            *(float4*)&Al[r * LDR + c] = v;
        }
    }
    // W transpose: Bl[nn*LDR + k] = (half)W[k*BN + nn]
#pragma unroll
    for (int q = 0; q < (K * BN / 4) / 256; ++q) {
        int fi = q * 256 + tid;
        int k = fi / (BN / 4), n4 = (fi % (BN / 4)) * 4;
        float4 v = *(const float4*)(W + (size_t)k * BN + n4);
        Bl[(n4 + 0) * LDR + k] = __float2half(v.x);
        Bl[(n4 + 1) * LDR + k] = __float2half(v.y);
        Bl[(n4 + 2) * LDR + k] = __float2half(v.z);
        Bl[(n4 + 3) * LDR + k] = __float2half(v.w);
    }
    __syncthreads();
    const int wid = tid >> 6, lane = tid & 63;
    const int lo = lane & 15, hi = lane >> 4;
    constexpr int NC = BN / 16;
    f32x4 acc[2][NC];
#pragma unroll
    for (int t = 0; t < 2; ++t)
#pragma unroll
        for (int c = 0; c < NC; ++c) acc[t][c] = (f32x4){0.f, 0.f, 0.f, 0.f};
#pragma unroll
    for (int kc = 0; kc < 4; ++kc) {
        h8 aF[2];
#pragma unroll
        for (int t = 0; t < 2; ++t)
            aF[t] = *(const h8*)&Al[(32 * wid + 16 * t + lo) * LDR + 32 * kc + 8 * hi];
#pragma unroll
        for (int c = 0; c < NC; ++c) {
            h8 bF = *(const h8*)&Bl[(16 * c + lo) * LDR + 32 * kc + 8 * hi];
#pragma unroll
            for (int t = 0; t < 2; ++t)
                acc[t][c] = __builtin_amdgcn_mfma_f32_16x16x32_f16(aF[t], bF, acc[t][c], 0, 0, 0);
        }
    }
#pragma unroll
    for (int t = 0; t < 2; ++t) {
#pragma unroll
        for (int j = 0; j < 4; ++j) {
            int gr = row0 + 32 * wid + 16 * t + 4 * hi + j;
            if (gr < n) {
#pragma unroll
                for (int c = 0; c < NC; ++c)
                    C[(size_t)gr * BN + 16 * c + lo] = __float2half(acc[t][c][j]);
            }
        }
    }
}

// ---------------- fused: {count degrees + pos} || {GEMM0: Hu = feat @ W0} ----------------
__global__ __launch_bounds__(256) void k_fused0(
        const float* __restrict__ feat, const float* __restrict__ W0,
        __half* __restrict__ Hu, int n,
        const int* __restrict__ src, const int* __restrict__ dst, int E,
        int* __restrict__ deg_o, int* __restrict__ deg_i, int* __restrict__ pos,
        int CB, int T) {
    const int b = blockIdx.x;
    const long lo = (long)b * CB / T, hi = (long)(b + 1) * CB / T;
    if (hi > lo) {  // count block, Bresenham-interleaved with GEMM blocks
        int i = (int)lo * 256 + threadIdx.x;
        const int stride = CB * 256;
        for (; i < E; i += stride) {
            atomicAdd(&deg_o[src[i]], 1);
            pos[i] = atomicAdd(&deg_i[dst[i]], 1);
        }
    } else {
        gemm_body<128, true>(feat, W0, Hu, n, b - (int)lo);
    }
}

// ---------------- plain GEMM (layers 1,2) ----------------
template <int BN>
__global__ __launch_bounds__(256) void k_gemm(const __half* __restrict__ X,
                                              const float* __restrict__ W,
                                              __half* __restrict__ C, int n) {
    gemm_body<BN, false>(X, W, C, n, blockIdx.x);
}

// ---------------- scan1 + norms fused ----------------
__global__ __launch_bounds__(256) void k_scan1(const int* __restrict__ deg_i,
                                               const int* __restrict__ deg_o,
                                               int* __restrict__ rp,
                                               int* __restrict__ bsum,
                                               float* __restrict__ ns,
                                               float* __restrict__ nd, int n) {
    const int tid = threadIdx.x, lane = tid & 63, wid = tid >> 6;
    int i = blockIdx.x * 256 + tid;
    int v = (i < n) ? deg_i[i] : 0;
    if (i < n) {
        nd[i] = rsqrtf((float)max(v, 1));
        ns[i] = rsqrtf((float)max(deg_o[i], 1));
    }
    int x = v;
#pragma unroll
    for (int off = 1; off < 64; off <<= 1) {
        int t = __shfl_up(x, off, 64);
        if (lane >= off) x += t;
    }
    __shared__ int ws[4];
    if (lane == 63) ws[wid] = x;
    __syncthreads();
    int wo = 0;
    for (int k = 0; k < wid; ++k) wo += ws[k];
    int incl = wo + x;
    if (i < n) rp[i] = incl - v;              // block-local exclusive
    if (tid == 255) bsum[blockIdx.x] = incl;  // block total
}

// scan of block sums; rp[N] fixed so that rp[N] + bsum[nb-1] == E
__global__ __launch_bounds__(512) void k_scan2(int* __restrict__ bsum, int nb,
                                               int* __restrict__ rpN) {
    __shared__ int s[512];
    const int tid = threadIdx.x;
    int v = (tid < nb) ? bsum[tid] : 0;
    s[tid] = v;
    __syncthreads();
    for (int off = 1; off < 512; off <<= 1) {
        int t = (tid >= off) ? s[tid - off] : 0;
        __syncthreads();
        s[tid] += t;
        __syncthreads();
    }
    if (tid < nb) bsum[tid] = s[tid] - v;  // exclusive block offsets
    if (tid == nb - 1) *rpN = v;           // last block's local total
}

// ---------------- CSR scatter (no atomics; rp is block-local + bsum) ----------------
__global__ void k_scatter(const int* __restrict__ src, const int* __restrict__ dst, int E,
                          const int* __restrict__ rp, const int* __restrict__ bsum,
                          const int* __restrict__ pos, int* __restrict__ csr) {
    int i = blockIdx.x * blockDim.x + threadIdx.x;
    int stride = gridDim.x * blockDim.x;
    for (; i < E; i += stride) {
        int d = dst[i];
        csr[rp[d] + bsum[d >> 8] + pos[i]] = src[i];
    }
}

// ---------------- aggregation D=128 fp16 in/out ----------------
// SSCALE: fold ns[src] per-edge (layer 0, H unscaled). Output pre-scaled by ns[node].
template <bool RELU, bool SSCALE>
__global__ __launch_bounds__(256) void k_agg128h(const __half2* __restrict__ H,  // [N][64]
                                                 const int* __restrict__ rp,
                                                 const int* __restrict__ bsum,
                                                 const int* __restrict__ cs,
                                                 const float* __restrict__ nd,
                                                 const float* __restrict__ ns,
                                                 const float* __restrict__ b,
                                                 __half2* __restrict__ out, int n) {
    const int wid = threadIdx.x >> 6, lane = threadIdx.x & 63;
    const int node = blockIdx.x * 4 + wid;
    if (node >= n) return;
    const int beg = rp[node] + bsum[node >> 8];
    const int end = rp[node + 1] + bsum[(node + 1) >> 8];
    float2 a0 = make_float2(0.f, 0.f), a1 = a0, a2 = a0, a3 = a0;
    int e = beg;
    for (; e + 3 < end; e += 4) {
        int s0 = cs[e], s1 = cs[e + 1], s2 = cs[e + 2], s3 = cs[e + 3];
        float w0 = SSCALE ? ns[s0] : 1.f;
        float w1 = SSCALE ? ns[s1] : 1.f;
        float w2 = SSCALE ? ns[s2] : 1.f;
        float w3 = SSCALE ? ns[s3] : 1.f;
        float2 v0 = __half22float2(H[(size_t)s0 * 64 + lane]);
        float2 v1 = __half22float2(H[(size_t)s1 * 64 + lane]);
        float2 v2 = __half22float2(H[(size_t)s2 * 64 + lane]);
        float2 v3 = __half22float2(H[(size_t)s3 * 64 + lane]);
        if (SSCALE) {
            a0.x = fmaf(v0.x, w0, a0.x); a0.y = fmaf(v0.y, w0, a0.y);
            a1.x = fmaf(v1.x, w1, a1.x); a1.y = fmaf(v1.y, w1, a1.y);
            a2.x = fmaf(v2.x, w2, a2.x); a2.y = fmaf(v2.y, w2, a2.y);
            a3.x = fmaf(v3.x, w3, a3.x); a3.y = fmaf(v3.y, w3, a3.y);
        } else {
            a0.x += v0.x; a0.y += v0.y;
            a1.x += v1.x; a1.y += v1.y;
            a2.x += v2.x; a2.y += v2.y;
            a3.x += v3.x; a3.y += v3.y;
        }
    }
    for (; e < end; ++e) {
        int s0 = cs[e];
        float w0 = SSCALE ? ns[s0] : 1.f;
        float2 v0 = __half22float2(H[(size_t)s0 * 64 + lane]);
        if (SSCALE) { a0.x = fmaf(v0.x, w0, a0.x); a0.y = fmaf(v0.y, w0, a0.y); }
        else        { a0.x += v0.x; a0.y += v0.y; }
    }
    const float sc = nd[node];
    const float sn = ns[node];
    float2 bb = ((const float2*)b)[lane];
    float ox = (a0.x + a1.x + a2.x + a3.x) * sc + bb.x;
    float oy = (a0.y + a1.y + a2.y + a3.y) * sc + bb.y;
    if (RELU) { ox = fmaxf(ox, 0.f); oy = fmaxf(oy, 0.f); }
    ox *= sn; oy *= sn;
    out[(size_t)node * 64 + lane] = __floats2half2_rn(ox, oy);
}

// ---------------- aggregation D=64 fp16 in, f32 out, no relu ----------------
__global__ __launch_bounds__(256) void k_agg64h(const __half* __restrict__ H,  // [N][64]
                                                const int* __restrict__ rp,
                                                const int* __restrict__ bsum,
                                                const int* __restrict__ cs,
                                                const float* __restrict__ nd,
                                                const float* __restrict__ b,
                                                float* __restrict__ out, int n) {
    const int wid = threadIdx.x >> 6, lane = threadIdx.x & 63;
    const int node = blockIdx.x * 4 + wid;
    if (node >= n) return;
    const int beg = rp[node] + bsum[node >> 8];
    const int end = rp[node + 1] + bsum[(node + 1) >> 8];
    float a0 = 0.f, a1 = 0.f, a2 = 0.f, a3 = 0.f;
    int e = beg;
    for (; e + 3 < end; e += 4) {
        a0 += __half2float(H[(size_t)cs[e] * 64 + lane]);
        a1 += __half2float(H[(size_t)cs[e + 1] * 64 + lane]);
        a2 += __half2float(H[(size_t)cs[e + 2] * 64 + lane]);
        a3 += __half2float(H[(size_t)cs[e + 3] * 64 + lane]);
    }
    for (; e < end; ++e) a0 += __half2float(H[(size_t)cs[e] * 64 + lane]);
    out[(size_t)node * 64 + lane] = (a0 + a1 + a2 + a3) * nd[node] + b[lane];
}

extern "C" void kernel_launch(void* const* d_in, const int* in_sizes, int n_in,
                              void* d_out, int out_size, void* d_ws, size_t ws_size,
                              hipStream_t stream) {
    const float* feat = (const float*)d_in[0];
    const int* ei = (const int*)d_in[1];
    const float* W0 = (const float*)d_in[2];
    const float* b0 = (const float*)d_in[3];
    const float* W1 = (const float*)d_in[4];
    const float* b1 = (const float*)d_in[5];
    const float* W2 = (const float*)d_in[6];
    const float* b2 = (const float*)d_in[7];
    float* out = (float*)d_out;

    const int N = in_sizes[0] / 128;  // 100000
    const int E = in_sizes[1] / 2;    // 1600000
    const int* src = ei;
    const int* dst = ei + E;
    const int NB = (N + 255) / 256;   // scan blocks (391 <= 512)

    // workspace layout (16B-aligned chunks)
    char* w = (char*)d_ws;
    float* norm_src = (float*)w; w += (size_t)N * 4;
    float* norm_dst = (float*)w; w += (size_t)N * 4;
    int* deg_o = (int*)w;        w += (size_t)N * 4;   // deg_o,deg_i contiguous (zero 2N)
    int* deg_i = (int*)w;        w += (size_t)N * 4;
    int* rp    = (int*)w;        w += ((size_t)(N + 1) * 4 + 15) / 16 * 16;
    int* bsum  = (int*)w;        w += 512 * 4;
    int* pos   = (int*)w;        w += (size_t)E * 4;
    int* csr   = (int*)w;        w += (size_t)E * 4;
    __half* Hb = (__half*)w;     w += (size_t)N * 128 * 2;  // GEMM out (gather src)
    __half* Xb = (__half*)w;     w += (size_t)N * 128 * 2;  // agg out / next GEMM in

    const int GB = (N + 127) / 128;   // 782 GEMM blocks
    const int CB = 1024;              // count blocks
    const int T = GB + CB;

    k_zero_i32<<<512, 256, 0, stream>>>(deg_o, 2 * N);
    // count || GEMM0 (Hu = feat @ W0, unscaled)
    k_fused0<<<T, 256, 0, stream>>>(feat, W0, Hb, N, src, dst, E, deg_o, deg_i, pos, CB, T);
    k_scan1<<<NB, 256, 0, stream>>>(deg_i, deg_o, rp, bsum, norm_src, norm_dst, N);
    k_scan2<<<1, 512, 0, stream>>>(bsum, NB, rp + N);
    k_scatter<<<2048, 256, 0, stream>>>(src, dst, E, rp, bsum, pos, csr);

    const int agg_grid = (N + 3) / 4;
    // layer 0: gather Hb with per-edge ns[src]; out pre-scaled by ns
    k_agg128h<true, true><<<agg_grid, 256, 0, stream>>>((const __half2*)Hb, rp, bsum, csr,
                                                        norm_dst, norm_src, b0, (__half2*)Xb, N);
    // layer 1
    k_gemm<128><<<GB, 256, 0, stream>>>(Xb, W1, Hb, N);
    k_agg128h<true, false><<<agg_grid, 256, 0, stream>>>((const __half2*)Hb, rp, bsum, csr,
                                                         norm_dst, norm_src, b1, (__half2*)Xb, N);
    // layer 2 (BN=64, no relu, f32 out)
    k_gemm<64><<<GB, 256, 0, stream>>>(Xb, W2, Hb, N);
    k_agg64h<<<agg_grid, 256, 0, stream>>>(Hb, rp, bsum, csr, norm_dst, b2, out, N);
}